// Round 1
// baseline (167.428 us; speedup 1.0000x reference)
//
#include <hip/hip_runtime.h>
#include <math.h>

// Problem constants (match reference)
#define GG 32
#define NN 64
#define TT 20
#define DIMH 64

static constexpr float EPSV = 1e-5f;
static constexpr float NEG_SLOPE = 0.1f;
static constexpr float SENSING_R = 2.0f;

#define TOTAL_E (GG * NN * NN * TT)   // 2,621,440

__global__ __launch_bounds__(256) void social_fused_kernel(
    const float* __restrict__ traj,    // [G*N, T, 2]
    const float* __restrict__ speed,   // [G*N, T, 2]
    const float* __restrict__ W1,      // [4, DIMH]
    const float* __restrict__ b1,      // [DIMH]
    const float* __restrict__ W2,      // [DIMH, 4]
    const float* __restrict__ b2,      // [4]
    const float* __restrict__ W3,      // [4, 2]
    const float* __restrict__ b3,      // [2]
    float* __restrict__ out_mask,      // [G,N,N,T] as float 0/1
    float* __restrict__ out_vec,       // [G,N,N,T,2]
    float cos_half_thr)
{
    int e = blockIdx.x * blockDim.x + threadIdx.x;
    if (e >= TOTAL_E) return;

    // e = ((g*N + i)*N + j)*T + t ; i = ego (first axis), j = neighbor
    int t  = e % TT;
    int ij = e / TT;
    int j  = ij % NN;
    int gi = ij / NN;          // g*N + i  (ego row in the flat [G*N] dim)
    int g  = gi / NN;
    int pj = g * NN + j;       // neighbor row

    // Loads (tiny inputs, L2-resident; float2 = 8B vectorized)
    const float2 Pi = *reinterpret_cast<const float2*>(traj  + (gi * TT + t) * 2);
    const float2 Pj = *reinterpret_cast<const float2*>(traj  + (pj * TT + t) * 2);
    const float2 Vi = *reinterpret_cast<const float2*>(speed + (gi * TT + t) * 2);

    float vecx = Pj.x - Pi.x;
    float vecy = Pj.y - Pi.y;
    float vix  = Vi.x;
    float viy  = Vi.y;

    // ---- mask: dist <= SENSING && acos(clip(dot/spd)) <= thr/2
    //      acos monotone decreasing on [-1,1]  =>  r >= cos(thr/2)
    float dist = sqrtf(vecx * vecx + vecy * vecy);
    float invd = 1.0f / (dist + EPSV);
    float dot  = (vix * vecx + viy * vecy) * invd;
    float spd  = sqrtf(vix * vix + viy * viy) + EPSV;
    float r    = dot / spd;
    r = fminf(1.0f, fmaxf(-1.0f, r));
    float maskf = (dist <= SENSING_R && r >= cos_half_thr) ? 1.0f : 0.0f;

    // ---- ResBlock MLP: h1 = leaky(feat @ W1 + b1); h2 = leaky(h1 @ W2 + b2)
    // feat = [vecx, vecy, vix, viy]
    // Fused k-loop: never materialize h1[64]; weights are wave-uniform -> s_load.
    float acc0 = b2[0], acc1 = b2[1], acc2 = b2[2], acc3 = b2[3];
#pragma unroll
    for (int k = 0; k < DIMH; ++k) {
        float h = b1[k];
        h = fmaf(vecx, W1[0 * DIMH + k], h);
        h = fmaf(vecy, W1[1 * DIMH + k], h);
        h = fmaf(vix,  W1[2 * DIMH + k], h);
        h = fmaf(viy,  W1[3 * DIMH + k], h);
        h = fmaxf(h, NEG_SLOPE * h);              // leaky_relu
        acc0 = fmaf(h, W2[k * 4 + 0], acc0);
        acc1 = fmaf(h, W2[k * 4 + 1], acc1);
        acc2 = fmaf(h, W2[k * 4 + 2], acc2);
        acc3 = fmaf(h, W2[k * 4 + 3], acc3);
    }
    float y0 = fmaxf(acc0, NEG_SLOPE * acc0) + vecx;
    float y1 = fmaxf(acc1, NEG_SLOPE * acc1) + vecy;
    float y2 = fmaxf(acc2, NEG_SLOPE * acc2) + vix;
    float y3 = fmaxf(acc3, NEG_SLOPE * acc3) + viy;

    // ---- head: sigmoid(y @ W3 + b3), W3 is [4][2] row-major
    float o0 = b3[0], o1 = b3[1];
    o0 = fmaf(y0, W3[0 * 2 + 0], o0);
    o1 = fmaf(y0, W3[0 * 2 + 1], o1);
    o0 = fmaf(y1, W3[1 * 2 + 0], o0);
    o1 = fmaf(y1, W3[1 * 2 + 1], o1);
    o0 = fmaf(y2, W3[2 * 2 + 0], o0);
    o1 = fmaf(y2, W3[2 * 2 + 1], o1);
    o0 = fmaf(y3, W3[3 * 2 + 0], o0);
    o1 = fmaf(y3, W3[3 * 2 + 1], o1);
    o0 = 1.0f / (1.0f + __expf(-o0));
    o1 = 1.0f / (1.0f + __expf(-o1));

    // ---- stores
    out_mask[e] = maskf;
    *reinterpret_cast<float2*>(out_vec + 2 * e) = make_float2(o0, o1);
}

extern "C" void kernel_launch(void* const* d_in, const int* in_sizes, int n_in,
                              void* d_out, int out_size, void* d_ws, size_t ws_size,
                              hipStream_t stream) {
    // setup_inputs() order: traj, speed, seq_start_end, W1, b1, W2, b2, W3, b3
    const float* traj  = (const float*)d_in[0];
    const float* speed = (const float*)d_in[1];
    // d_in[2] = seq_start_end (int32) — groups are contiguous & equal, unused
    const float* W1 = (const float*)d_in[3];
    const float* b1 = (const float*)d_in[4];
    const float* W2 = (const float*)d_in[5];
    const float* b2 = (const float*)d_in[6];
    const float* W3 = (const float*)d_in[7];
    const float* b3 = (const float*)d_in[8];

    float* out_mask = (float*)d_out;                 // [G,N,N,T]
    float* out_vec  = out_mask + TOTAL_E;            // [G,N,N,T,2]

    // ang <= ANGLE_THR/2  <=>  clipped cos-ratio >= cos(ANGLE_THR/2)
    const float cos_half_thr = cosf(0.5f * 0.8333f * 3.1415926f);

    const int block = 256;
    const int grid  = (TOTAL_E + block - 1) / block;  // 10240
    social_fused_kernel<<<grid, block, 0, stream>>>(
        traj, speed, W1, b1, W2, b2, W3, b3, out_mask, out_vec, cos_half_thr);
}

// Round 4
// 132.180 us; speedup vs baseline: 1.2667x; 1.2667x over previous
//
#include <hip/hip_runtime.h>
#include <math.h>

// Problem constants (match reference)
#define GG 32
#define NN 64
#define TT 20
#define DIMH 64

static constexpr float EPSV = 1e-5f;
static constexpr float NEG_SLOPE = 0.1f;
static constexpr float SENSING_R = 2.0f;

#define TOTAL_E (GG * NN * NN * TT)   // 2,621,440
#define EPT 4                          // elements (j's) per thread
#define NTHREADS (TOTAL_E / EPT)       // 655,360

__global__ __launch_bounds__(256) void social_fused_kernel(
    const float* __restrict__ traj,    // [G*N, T, 2]
    const float* __restrict__ speed,   // [G*N, T, 2]
    const float* __restrict__ W1,      // [4, DIMH]
    const float* __restrict__ b1,      // [DIMH]
    const float* __restrict__ W2,      // [DIMH, 4]
    const float* __restrict__ b2,      // [4]
    const float* __restrict__ W3,      // [4, 2]
    const float* __restrict__ b3,      // [2]
    float* __restrict__ out_mask,      // [G,N,N,T] as float 0/1
    float* __restrict__ out_vec,       // [G,N,N,T,2]
    float cos_half_thr)
{
    const int u = blockIdx.x * blockDim.x + threadIdx.x;
    if (u >= NTHREADS) return;

    // u = (gi*16 + j4)*20 + t ; thread covers j = 4*j4 .. 4*j4+3 for ego row gi at time t
    const int t  = u % TT;
    const int r2 = u / TT;
    const int j4 = r2 % (NN / EPT);
    const int gi = r2 / (NN / EPT);    // g*N + i
    const int g  = gi / NN;
    const int jb = g * NN + j4 * EPT;  // first neighbor row

    // Ego loads (shared by the 4 elements)
    const float2 Pi = *reinterpret_cast<const float2*>(traj  + (gi * TT + t) * 2);
    const float2 Vi = *reinterpret_cast<const float2*>(speed + (gi * TT + t) * 2);
    const float vix = Vi.x, viy = Vi.y;

    // Per-element relative positions
    float vecx[EPT], vecy[EPT];
#pragma unroll
    for (int d = 0; d < EPT; ++d) {
        const float2 Pj = *reinterpret_cast<const float2*>(traj + ((jb + d) * TT + t) * 2);
        vecx[d] = Pj.x - Pi.x;
        vecy[d] = Pj.y - Pi.y;
    }

    // ---- mask (exact same math as reference, acos replaced by monotone cos-compare)
    const float spd = sqrtf(vix * vix + viy * viy) + EPSV;
    float maskf[EPT];
#pragma unroll
    for (int d = 0; d < EPT; ++d) {
        float d2   = vecx[d] * vecx[d] + vecy[d] * vecy[d];
        float dist = sqrtf(d2);
        float dot  = (vix * vecx[d] + viy * vecy[d]) / (dist + EPSV);
        float r    = dot / spd;
        r = fminf(1.0f, fmaxf(-1.0f, r));
        maskf[d] = (dist <= SENSING_R && r >= cos_half_thr) ? 1.0f : 0.0f;
    }

    // ---- ResBlock MLP, k processed in chunks of 4 so weights load as float4
    float acc[EPT][4];
    const float bb0 = b2[0], bb1 = b2[1], bb2 = b2[2], bb3 = b2[3];
#pragma unroll
    for (int d = 0; d < EPT; ++d) {
        acc[d][0] = bb0; acc[d][1] = bb1; acc[d][2] = bb2; acc[d][3] = bb3;
    }

#pragma unroll
    for (int c = 0; c < DIMH / 4; ++c) {
        const int k0 = c * 4;
        const float4 w1r0 = *reinterpret_cast<const float4*>(W1 + 0 * DIMH + k0);
        const float4 w1r1 = *reinterpret_cast<const float4*>(W1 + 1 * DIMH + k0);
        const float4 w1r2 = *reinterpret_cast<const float4*>(W1 + 2 * DIMH + k0);
        const float4 w1r3 = *reinterpret_cast<const float4*>(W1 + 3 * DIMH + k0);
        const float4 b1c  = *reinterpret_cast<const float4*>(b1 + k0);
        const float4 w2r0 = *reinterpret_cast<const float4*>(W2 + (k0 + 0) * 4);
        const float4 w2r1 = *reinterpret_cast<const float4*>(W2 + (k0 + 1) * 4);
        const float4 w2r2 = *reinterpret_cast<const float4*>(W2 + (k0 + 2) * 4);
        const float4 w2r3 = *reinterpret_cast<const float4*>(W2 + (k0 + 3) * 4);

#pragma unroll
        for (int kk = 0; kk < 4; ++kk) {
            const float w0 = (kk == 0) ? w1r0.x : (kk == 1) ? w1r0.y : (kk == 2) ? w1r0.z : w1r0.w;
            const float w1 = (kk == 0) ? w1r1.x : (kk == 1) ? w1r1.y : (kk == 2) ? w1r1.z : w1r1.w;
            const float w2 = (kk == 0) ? w1r2.x : (kk == 1) ? w1r2.y : (kk == 2) ? w1r2.z : w1r2.w;
            const float w3 = (kk == 0) ? w1r3.x : (kk == 1) ? w1r3.y : (kk == 2) ? w1r3.z : w1r3.w;
            const float bk = (kk == 0) ? b1c.x  : (kk == 1) ? b1c.y  : (kk == 2) ? b1c.z  : b1c.w;
            const float4 w2r = (kk == 0) ? w2r0 : (kk == 1) ? w2r1 : (kk == 2) ? w2r2 : w2r3;

            // shared across the 4 elements: ego-velocity part of layer-1 pre-activation
            const float dsh = fmaf(vix, w2, fmaf(viy, w3, bk));
#pragma unroll
            for (int d = 0; d < EPT; ++d) {
                float h = fmaf(vecx[d], w0, fmaf(vecy[d], w1, dsh));
                h = fmaxf(h, NEG_SLOPE * h);            // leaky_relu
                acc[d][0] = fmaf(h, w2r.x, acc[d][0]);
                acc[d][1] = fmaf(h, w2r.y, acc[d][1]);
                acc[d][2] = fmaf(h, w2r.z, acc[d][2]);
                acc[d][3] = fmaf(h, w2r.w, acc[d][3]);
            }
        }
    }

    // ---- residual + head + sigmoid + stores
    const float w300 = W3[0], w301 = W3[1], w310 = W3[2], w311 = W3[3];
    const float w320 = W3[4], w321 = W3[5], w330 = W3[6], w331 = W3[7];
    const float bo0 = b3[0], bo1 = b3[1];

    const long long ebase = ((long long)gi * NN + (j4 * EPT)) * TT + t;
#pragma unroll
    for (int d = 0; d < EPT; ++d) {
        float y0 = fmaxf(acc[d][0], NEG_SLOPE * acc[d][0]) + vecx[d];
        float y1 = fmaxf(acc[d][1], NEG_SLOPE * acc[d][1]) + vecy[d];
        float y2 = fmaxf(acc[d][2], NEG_SLOPE * acc[d][2]) + vix;
        float y3 = fmaxf(acc[d][3], NEG_SLOPE * acc[d][3]) + viy;

        float o0 = bo0, o1 = bo1;
        o0 = fmaf(y0, w300, o0);  o1 = fmaf(y0, w301, o1);
        o0 = fmaf(y1, w310, o0);  o1 = fmaf(y1, w311, o1);
        o0 = fmaf(y2, w320, o0);  o1 = fmaf(y2, w321, o1);
        o0 = fmaf(y3, w330, o0);  o1 = fmaf(y3, w331, o1);
        o0 = 1.0f / (1.0f + __expf(-o0));
        o1 = 1.0f / (1.0f + __expf(-o1));

        const long long e = ebase + (long long)d * TT;   // j stride in element space
        out_mask[e] = maskf[d];
        *reinterpret_cast<float2*>(out_vec + 2 * e) = make_float2(o0, o1);
    }
}

extern "C" void kernel_launch(void* const* d_in, const int* in_sizes, int n_in,
                              void* d_out, int out_size, void* d_ws, size_t ws_size,
                              hipStream_t stream) {
    // setup_inputs() order: traj, speed, seq_start_end, W1, b1, W2, b2, W3, b3
    const float* traj  = (const float*)d_in[0];
    const float* speed = (const float*)d_in[1];
    // d_in[2] = seq_start_end (int32) — groups are contiguous & equal, unused
    const float* W1 = (const float*)d_in[3];
    const float* b1 = (const float*)d_in[4];
    const float* W2 = (const float*)d_in[5];
    const float* b2 = (const float*)d_in[6];
    const float* W3 = (const float*)d_in[7];
    const float* b3 = (const float*)d_in[8];

    float* out_mask = (float*)d_out;                 // [G,N,N,T]
    float* out_vec  = out_mask + TOTAL_E;            // [G,N,N,T,2]

    // ang <= ANGLE_THR/2  <=>  clipped cos-ratio >= cos(ANGLE_THR/2)
    const float cos_half_thr = cosf(0.5f * 0.8333f * 3.1415926f);

    const int block = 256;
    const int grid  = (NTHREADS + block - 1) / block;  // 2560
    social_fused_kernel<<<grid, block, 0, stream>>>(
        traj, speed, W1, b1, W2, b2, W3, b3, out_mask, out_vec, cos_half_thr);
}

// Round 5
// 129.416 us; speedup vs baseline: 1.2937x; 1.0214x over previous
//
#include <hip/hip_runtime.h>
#include <math.h>

// Problem constants (match reference)
#define GG 32
#define NP 64
#define TT 20
#define DIMH 64
#define TOTAL_E (GG * NP * NP * TT)   // 2,621,440
#define TILES_PER_WAVE 8               // 32 elements per tile -> 256 el/wave

static constexpr float EPSV = 1e-5f;
static constexpr float SENSING_R = 2.0f;

typedef __attribute__((ext_vector_type(8)))  short    bf16x8;   // 4 VGPRs = 8 bf16 (MFMA A/B)
typedef __attribute__((ext_vector_type(16))) float    f32x16;   // MFMA C/D
typedef __attribute__((ext_vector_type(4)))  unsigned u32x4;

// pack two f32 -> one u32 of 2 bf16 (lo = src0, hi = src1); no builtin on gfx950 (m240)
static __device__ __forceinline__ unsigned cvtpk(float lo, float hi) {
    unsigned r;
    asm("v_cvt_pk_bf16_f32 %0, %1, %2" : "=v"(r) : "v"(lo), "v"(hi));
    return r;
}
static __device__ __forceinline__ float bflo2f(unsigned w) { return __uint_as_float(w << 16); }
static __device__ __forceinline__ float bfhi2f(unsigned w) { return __uint_as_float(w & 0xffff0000u); }
static __device__ __forceinline__ float lrelu(float x) { return fmaxf(x, 0.1f * x); }

// Layer-1 A fragment: A[row=n, kslot] for one 32-n half, triple-packed split:
//   kslots 0-3 = bf16_hi(W1[k,n]), 4-7 = bf16_hi again (pairs fl), 8-11 = bf16_lo-resid, 12-15 = 0
// 32x32x16 A layout: lane l holds row=l&31, k = 8*(l>>5)+j  (j = 0..7, word w_j = k {2j,2j+1})
static __device__ __forceinline__ bf16x8 makeA1(const float* W1, int n, int hi) {
    float c0 = W1[0 * DIMH + n], c1 = W1[1 * DIMH + n], c2 = W1[2 * DIMH + n], c3 = W1[3 * DIMH + n];
    unsigned wh0 = cvtpk(c0, c1), wh1 = cvtpk(c2, c3);
    unsigned wl0 = cvtpk(c0 - bflo2f(wh0), c1 - bfhi2f(wh0));
    unsigned wl1 = cvtpk(c2 - bflo2f(wh1), c3 - bfhi2f(wh1));
    u32x4 p;
    p.x = hi ? wl0 : wh0;  p.y = hi ? wl1 : wh1;
    p.z = hi ? 0u  : wh0;  p.w = hi ? 0u  : wh1;
    return __builtin_bit_cast(bf16x8, p);
}

// Layer-2 A chunk C (K=16 of n): A[row=m(<4), k=16C+8*hi+j] = W2[k, m]; rows 4-31 zero
template <int C>
static __device__ __forceinline__ bf16x8 makeWA(const float* W2, int hi, int l31) {
    const bool mv = (l31 < 4);
    float q[8];
#pragma unroll
    for (int jj = 0; jj < 8; ++jj) {
        int k = 16 * C + 8 * hi + jj;
        q[jj] = mv ? W2[k * 4 + l31] : 0.0f;
    }
    u32x4 p;
    p.x = cvtpk(q[0], q[1]); p.y = cvtpk(q[2], q[3]);
    p.z = cvtpk(q[4], q[5]); p.w = cvtpk(q[6], q[7]);
    return __builtin_bit_cast(bf16x8, p);
}

__global__ __launch_bounds__(256) void social_mfma_kernel(
    const float* __restrict__ traj,    // [G*N, T, 2]
    const float* __restrict__ speed,   // [G*N, T, 2]
    const float* __restrict__ W1,      // [4, 64]
    const float* __restrict__ b1,      // [64]
    const float* __restrict__ W2,      // [64, 4]
    const float* __restrict__ b2,      // [4]
    const float* __restrict__ W3,      // [4, 2]
    const float* __restrict__ b3,      // [2]
    float* __restrict__ out_mask,      // [G,N,N,T] 0/1 floats
    float* __restrict__ out_vec,       // [G,N,N,T,2]
    float cos_half_thr)
{
    const int tid  = threadIdx.x;
    const int lane = tid & 63;
    const int l31  = lane & 31;
    const int hi   = lane >> 5;
    const int wgid = blockIdx.x * 4 + (tid >> 6);
    const int e0   = wgid * (TILES_PER_WAVE * 32);

    // ---- one-time per-wave weight fragments ----
    const bf16x8 A1 = makeA1(W1, l31, hi);         // n = 0..31
    const bf16x8 A2 = makeA1(W1, 32 + l31, hi);    // n = 32..63
    const bf16x8 WA0 = makeWA<0>(W2, hi, l31);
    const bf16x8 WA1 = makeWA<1>(W2, hi, l31);
    const bf16x8 WA2 = makeWA<2>(W2, hi, l31);
    const bf16x8 WA3 = makeWA<3>(W2, hi, l31);

    // bias fragments: C/D row = (r&3)+8*(r>>2)+4*hi, col = lane&31 (m74/m101 verified)
    f32x16 C1, C2;
#pragma unroll
    for (int r = 0; r < 16; ++r) {
        int n = (r & 3) + 8 * (r >> 2) + 4 * hi;
        C1[r] = b1[n];
        C2[r] = b1[n + 32];
    }
    f32x16 CY0 = {};   // layer2 C-in: b2 on rows m=0..3 (hi=0, regs 0..3), else 0
    if (hi == 0) { CY0[0] = b2[0]; CY0[1] = b2[1]; CY0[2] = b2[2]; CY0[3] = b2[3]; }

    const float w300 = W3[0], w301 = W3[1], w310 = W3[2], w311 = W3[3];
    const float w320 = W3[4], w321 = W3[5], w330 = W3[6], w331 = W3[7];
    const float bo0 = b3[0], bo1 = b3[1];

#pragma unroll 1
    for (int tile = 0; tile < TILES_PER_WAVE; ++tile) {
        // element for this lane: both half-waves mirror the same 32 elements
        const int e   = e0 + tile * 32 + l31;
        const int t   = e % TT;
        const int q20 = e / TT;            // = gi*64 + j
        const int j   = q20 & 63;
        const int gi  = q20 >> 6;
        const int pjr = (gi & ~63) + j;    // g*64 + j

        const float2 Pi = *reinterpret_cast<const float2*>(traj  + (gi  * TT + t) * 2);
        const float2 Vi = *reinterpret_cast<const float2*>(speed + (gi  * TT + t) * 2);
        const float2 Pj = *reinterpret_cast<const float2*>(traj  + (pjr * TT + t) * 2);
        const float vecx = Pj.x - Pi.x, vecy = Pj.y - Pi.y;
        const float vix = Vi.x, viy = Vi.y;

        // ---- layer1 B fragment (feat^T), split fh/fl; kslots {fh,fl,fh-dup} ----
        // B layout: lane l: col=l&31, k=8*(l>>5)+j. hi=0: k0-7 = [fh|fl]; hi=1: k8-15 = [fh|0]
        unsigned f0 = cvtpk(vecx, vecy), f1 = cvtpk(vix, viy);
        unsigned f2 = cvtpk(vecx - bflo2f(f0), vecy - bfhi2f(f0));
        unsigned f3 = cvtpk(vix  - bflo2f(f1), viy  - bfhi2f(f1));
        u32x4 bp;
        bp.x = f0; bp.y = f1;
        bp.z = hi ? 0u : f2; bp.w = hi ? 0u : f3;
        const bf16x8 Bf = __builtin_bit_cast(bf16x8, bp);

        // ---- layer1: h^T[n, e] = W1^T·feat^T + b1 ----
        f32x16 H1 = __builtin_amdgcn_mfma_f32_32x32x16_bf16(A1, Bf, C1, 0, 0, 0);
        f32x16 H2 = __builtin_amdgcn_mfma_f32_32x32x16_bf16(A2, Bf, C2, 0, 0, 0);

        // ---- leaky + pack to bf16 pair-words (n ascending pairs per D layout) ----
        unsigned u[16];
#pragma unroll
        for (int m = 0; m < 8; ++m) {
            float a = lrelu(H1[2 * m]), b = lrelu(H1[2 * m + 1]);
            u[m] = cvtpk(a, b);
        }
#pragma unroll
        for (int m = 0; m < 8; ++m) {
            float a = lrelu(H2[2 * m]), b = lrelu(H2[2 * m + 1]);
            u[8 + m] = cvtpk(a, b);
        }

        // ---- relayout D->B via lane^32 exchange; layer2: y^T = W2^T·h^T + b2 ----
        f32x16 Y = CY0;
#define L2STEP(c, WAc)                                                        \
        {                                                                     \
            int s0 = __shfl_xor((int)u[4 * c + 0], 32);                       \
            int s1 = __shfl_xor((int)u[4 * c + 1], 32);                       \
            int s2 = __shfl_xor((int)u[4 * c + 2], 32);                       \
            int s3 = __shfl_xor((int)u[4 * c + 3], 32);                       \
            u32x4 bb;                                                         \
            bb.x = hi ? (unsigned)s2 : u[4 * c + 0];                          \
            bb.y = hi ? (unsigned)s3 : u[4 * c + 1];                          \
            bb.z = hi ? u[4 * c + 2] : (unsigned)s0;                          \
            bb.w = hi ? u[4 * c + 3] : (unsigned)s1;                          \
            bf16x8 B2 = __builtin_bit_cast(bf16x8, bb);                       \
            Y = __builtin_amdgcn_mfma_f32_32x32x16_bf16(WAc, B2, Y, 0, 0, 0); \
        }
        L2STEP(0, WA0) L2STEP(1, WA1) L2STEP(2, WA2) L2STEP(3, WA3)
#undef L2STEP

        // ---- epilogue: lanes<32 hold y[m=0..3] for element e in Y[0..3] ----
        if (hi == 0) {
            float y0 = lrelu(Y[0]) + vecx;
            float y1 = lrelu(Y[1]) + vecy;
            float y2 = lrelu(Y[2]) + vix;
            float y3 = lrelu(Y[3]) + viy;

            float o0 = bo0, o1 = bo1;
            o0 = fmaf(y0, w300, o0);  o1 = fmaf(y0, w301, o1);
            o0 = fmaf(y1, w310, o0);  o1 = fmaf(y1, w311, o1);
            o0 = fmaf(y2, w320, o0);  o1 = fmaf(y2, w321, o1);
            o0 = fmaf(y3, w330, o0);  o1 = fmaf(y3, w331, o1);
            o0 = __fdividef(1.0f, 1.0f + __expf(-o0));
            o1 = __fdividef(1.0f, 1.0f + __expf(-o1));

            // mask: bit-identical expressions to the passing R1 kernel
            float spd  = sqrtf(vix * vix + viy * viy) + EPSV;
            float d2   = vecx * vecx + vecy * vecy;
            float dist = sqrtf(d2);
            float dot  = (vix * vecx + viy * vecy) / (dist + EPSV);
            float r    = dot / spd;
            r = fminf(1.0f, fmaxf(-1.0f, r));
            float mk = (dist <= SENSING_R && r >= cos_half_thr) ? 1.0f : 0.0f;

            out_mask[e] = mk;
            *reinterpret_cast<float2*>(out_vec + 2 * e) = make_float2(o0, o1);
        }
    }
}

extern "C" void kernel_launch(void* const* d_in, const int* in_sizes, int n_in,
                              void* d_out, int out_size, void* d_ws, size_t ws_size,
                              hipStream_t stream) {
    // setup_inputs() order: traj, speed, seq_start_end, W1, b1, W2, b2, W3, b3
    const float* traj  = (const float*)d_in[0];
    const float* speed = (const float*)d_in[1];
    // d_in[2] = seq_start_end — groups contiguous & equal, unused
    const float* W1 = (const float*)d_in[3];
    const float* b1 = (const float*)d_in[4];
    const float* W2 = (const float*)d_in[5];
    const float* b2 = (const float*)d_in[6];
    const float* W3 = (const float*)d_in[7];
    const float* b3 = (const float*)d_in[8];

    float* out_mask = (float*)d_out;          // [G,N,N,T]
    float* out_vec  = out_mask + TOTAL_E;     // [G,N,N,T,2]

    const float cos_half_thr = cosf(0.5f * 0.8333f * 3.1415926f);

    // 1 wave = 256 elements; 4 waves/block => 1024 el/block; grid exact
    const int block = 256;
    const int grid  = TOTAL_E / 1024;         // 2560
    social_mfma_kernel<<<grid, block, 0, stream>>>(
        traj, speed, W1, b1, W2, b2, W3, b3, out_mask, out_vec, cos_half_thr);
}

// Round 11
// 123.330 us; speedup vs baseline: 1.3576x; 1.0493x over previous
//
#include <hip/hip_runtime.h>
#include <math.h>

// Problem constants (match reference)
#define GG 32
#define NP 64
#define TT 20
#define DIMH 64
#define TOTAL_E (GG * NP * NP * TT)   // 2,621,440
#define TILES_PER_WAVE 8               // 32 elements per tile -> 256 el/wave

static constexpr float EPSV = 1e-5f;
static constexpr float SENSING_R = 2.0f;

typedef __attribute__((ext_vector_type(8)))  short    bf16x8;   // 4 VGPRs = 8 bf16 (MFMA A/B)
typedef __attribute__((ext_vector_type(16))) float    f32x16;   // MFMA C/D
typedef __attribute__((ext_vector_type(4)))  unsigned u32x4;

// pack two f32 -> one u32 of 2 bf16 (lo = src0, hi = src1); no builtin on gfx950 (m240)
static __device__ __forceinline__ unsigned cvtpk(float lo, float hi) {
    unsigned r;
    asm("v_cvt_pk_bf16_f32 %0, %1, %2" : "=v"(r) : "v"(lo), "v"(hi));
    return r;
}
static __device__ __forceinline__ float bflo2f(unsigned w) { return __uint_as_float(w << 16); }
static __device__ __forceinline__ float bfhi2f(unsigned w) { return __uint_as_float(w & 0xffff0000u); }
static __device__ __forceinline__ float lrelu(float x) { return fmaxf(x, 0.1f * x); }

// Layer-1 A fragment: A[row=n, kslot] for one 32-n half, triple-packed split:
//   hi=0 lanes: k0-3 = W1_hi, k4-7 = W1_hi (pairs feat_lo); hi=1: k8-11 = W1_lo (pairs feat_hi)
// 32x32x16 A layout: lane l holds row=l&31, k = 8*(l>>5)+j (word w = k {2w,2w+1})
static __device__ __forceinline__ bf16x8 makeA1(const float* W1, int n, int hi) {
    float c0 = W1[0 * DIMH + n], c1 = W1[1 * DIMH + n], c2 = W1[2 * DIMH + n], c3 = W1[3 * DIMH + n];
    unsigned wh0 = cvtpk(c0, c1), wh1 = cvtpk(c2, c3);
    unsigned wl0 = cvtpk(c0 - bflo2f(wh0), c1 - bfhi2f(wh0));
    unsigned wl1 = cvtpk(c2 - bflo2f(wh1), c3 - bfhi2f(wh1));
    u32x4 p;
    p.x = hi ? wl0 : wh0;  p.y = hi ? wl1 : wh1;
    p.z = hi ? 0u  : wh0;  p.w = hi ? 0u  : wh1;
    return __builtin_bit_cast(bf16x8, p);
}

// Channel-pair base held in u-word m (from verified D layout: row=(r&3)+8*(r>>2)+4hi):
//   u[m] holds channels (tab[m]+4hi, tab[m]+4hi+1); m>=8 -> H2 (+32 baked into tab)
// Layer-2 k-slot K = 16c + 8hi + 2w + eps consumes u-word m=4c+w
//   => W2-row for that slot is ch(K) = tab[4c+w] + 4hi + eps (bijective over 0..63)
// Layer-2 A chunk C: A[row=m_out(<4), k_local=8hi+jj] = W2[ch][m_out]; rows 4-31 zero
template <int C>
static __device__ __forceinline__ bf16x8 makeWA(const float* W2, int hi, int l31) {
    constexpr int tab[16] = {0,2,8,10,16,18,24,26,32,34,40,42,48,50,56,58};
    const bool mv = (l31 < 4);
    float q[8];
#pragma unroll
    for (int jj = 0; jj < 8; ++jj) {
        const int ch = tab[4 * C + (jj >> 1)] + 4 * hi + (jj & 1);
        q[jj] = mv ? W2[ch * 4 + l31] : 0.0f;
    }
    u32x4 p;
    p.x = cvtpk(q[0], q[1]); p.y = cvtpk(q[2], q[3]);
    p.z = cvtpk(q[4], q[5]); p.w = cvtpk(q[6], q[7]);
    return __builtin_bit_cast(bf16x8, p);
}

__global__ __launch_bounds__(256) void social_mfma_kernel(
    const float* __restrict__ traj,    // [G*N, T, 2]
    const float* __restrict__ speed,   // [G*N, T, 2]
    const float* __restrict__ W1,      // [4, 64]
    const float* __restrict__ b1,      // [64]
    const float* __restrict__ W2,      // [64, 4]
    const float* __restrict__ b2,      // [4]
    const float* __restrict__ W3,      // [4, 2]
    const float* __restrict__ b3,      // [2]
    float* __restrict__ out_mask,      // [G,N,N,T] 0/1 floats
    float* __restrict__ out_vec,       // [G,N,N,T,2]
    float cos_half_thr)
{
    const int tid  = threadIdx.x;
    const int lane = tid & 63;
    const int l31  = lane & 31;
    const int hi   = lane >> 5;
    const int wgid = blockIdx.x * 4 + (tid >> 6);
    const int e0   = wgid * (TILES_PER_WAVE * 32);

    // ---- one-time per-wave weight fragments ----
    const bf16x8 A1 = makeA1(W1, l31, hi);         // channels 0..31
    const bf16x8 A2 = makeA1(W1, 32 + l31, hi);    // channels 32..63
    const bf16x8 WA0 = makeWA<0>(W2, hi, l31);
    const bf16x8 WA1 = makeWA<1>(W2, hi, l31);
    const bf16x8 WA2 = makeWA<2>(W2, hi, l31);
    const bf16x8 WA3 = makeWA<3>(W2, hi, l31);

    // bias fragments: C/D row = (r&3)+8*(r>>2)+4*hi, col = lane&31 (m74/m101 verified)
    f32x16 C1, C2;
#pragma unroll
    for (int r = 0; r < 16; ++r) {
        int n = (r & 3) + 8 * (r >> 2) + 4 * hi;
        C1[r] = b1[n];
        C2[r] = b1[n + 32];
    }
    f32x16 CY0 = {};   // layer2 C-in: b2 on rows m=0..3 (hi=0, regs 0..3), else 0
    if (hi == 0) { CY0[0] = b2[0]; CY0[1] = b2[1]; CY0[2] = b2[2]; CY0[3] = b2[3]; }

    const float w300 = W3[0], w301 = W3[1], w310 = W3[2], w311 = W3[3];
    const float w320 = W3[4], w321 = W3[5], w330 = W3[6], w331 = W3[7];
    const float bo0 = b3[0], bo1 = b3[1];

#pragma unroll 1
    for (int tile = 0; tile < TILES_PER_WAVE; ++tile) {
        // element for this lane: both half-waves mirror the same 32 elements
        const int e   = e0 + tile * 32 + l31;
        const int t   = e % TT;
        const int q20 = e / TT;            // = gi*64 + j
        const int j   = q20 & 63;
        const int gi  = q20 >> 6;
        const int pjr = (gi & ~63) + j;    // g*64 + j

        const float2 Pi = *reinterpret_cast<const float2*>(traj  + (gi  * TT + t) * 2);
        const float2 Vi = *reinterpret_cast<const float2*>(speed + (gi  * TT + t) * 2);
        const float2 Pj = *reinterpret_cast<const float2*>(traj  + (pjr * TT + t) * 2);
        const float vecx = Pj.x - Pi.x, vecy = Pj.y - Pi.y;
        const float vix = Vi.x, viy = Vi.y;

        // ---- layer1 B fragment (feat^T), split fh/fl; kslots {fh,fl | fh,0} ----
        unsigned f0 = cvtpk(vecx, vecy), f1 = cvtpk(vix, viy);
        unsigned f2 = cvtpk(vecx - bflo2f(f0), vecy - bfhi2f(f0));
        unsigned f3 = cvtpk(vix  - bflo2f(f1), viy  - bfhi2f(f1));
        u32x4 bp;
        bp.x = f0; bp.y = f1;
        bp.z = hi ? 0u : f2; bp.w = hi ? 0u : f3;
        const bf16x8 Bf = __builtin_bit_cast(bf16x8, bp);

        // ---- layer1: h^T[n, e] = W1^T·feat^T + b1 ----
        f32x16 H1 = __builtin_amdgcn_mfma_f32_32x32x16_bf16(A1, Bf, C1, 0, 0, 0);
        f32x16 H2 = __builtin_amdgcn_mfma_f32_32x32x16_bf16(A2, Bf, C2, 0, 0, 0);

        // ---- leaky + pack to bf16 pair-words (channel pairs per D layout) ----
        unsigned u[16];
#pragma unroll
        for (int m = 0; m < 8; ++m) {
            float a = lrelu(H1[2 * m]), b = lrelu(H1[2 * m + 1]);
            u[m] = cvtpk(a, b);
        }
#pragma unroll
        for (int m = 0; m < 8; ++m) {
            float a = lrelu(H2[2 * m]), b = lrelu(H2[2 * m + 1]);
            u[8 + m] = cvtpk(a, b);
        }

        // ---- layer2: y^T = W2^T·h^T + b2 ; B2 = u-words DIRECTLY (no shuffles):
        //      channel permutation is absorbed into WA fragments (see makeWA)
        f32x16 Y = CY0;
#define L2STEP(c, WAc)                                                        \
        {                                                                     \
            u32x4 bb;                                                         \
            bb.x = u[4 * c + 0]; bb.y = u[4 * c + 1];                         \
            bb.z = u[4 * c + 2]; bb.w = u[4 * c + 3];                         \
            bf16x8 B2 = __builtin_bit_cast(bf16x8, bb);                       \
            Y = __builtin_amdgcn_mfma_f32_32x32x16_bf16(WAc, B2, Y, 0, 0, 0); \
        }
        L2STEP(0, WA0) L2STEP(1, WA1) L2STEP(2, WA2) L2STEP(3, WA3)
#undef L2STEP

        // ---- epilogue: lanes<32 hold y[m=0..3] for element e in Y[0..3] ----
        if (hi == 0) {
            float y0 = lrelu(Y[0]) + vecx;
            float y1 = lrelu(Y[1]) + vecy;
            float y2 = lrelu(Y[2]) + vix;
            float y3 = lrelu(Y[3]) + viy;

            float o0 = bo0, o1 = bo1;
            o0 = fmaf(y0, w300, o0);  o1 = fmaf(y0, w301, o1);
            o0 = fmaf(y1, w310, o0);  o1 = fmaf(y1, w311, o1);
            o0 = fmaf(y2, w320, o0);  o1 = fmaf(y2, w321, o1);
            o0 = fmaf(y3, w330, o0);  o1 = fmaf(y3, w331, o1);
            o0 = __fdividef(1.0f, 1.0f + __expf(-o0));
            o1 = __fdividef(1.0f, 1.0f + __expf(-o1));

            // mask: bit-identical expressions to the passing R1/R4 kernels
            float spd  = sqrtf(vix * vix + viy * viy) + EPSV;
            float d2   = vecx * vecx + vecy * vecy;
            float dist = sqrtf(d2);
            float dot  = (vix * vecx + viy * vecy) / (dist + EPSV);
            float r    = dot / spd;
            r = fminf(1.0f, fmaxf(-1.0f, r));
            float mk = (dist <= SENSING_R && r >= cos_half_thr) ? 1.0f : 0.0f;

            out_mask[e] = mk;
            *reinterpret_cast<float2*>(out_vec + 2 * e) = make_float2(o0, o1);
        }
    }
}

extern "C" void kernel_launch(void* const* d_in, const int* in_sizes, int n_in,
                              void* d_out, int out_size, void* d_ws, size_t ws_size,
                              hipStream_t stream) {
    // setup_inputs() order: traj, speed, seq_start_end, W1, b1, W2, b2, W3, b3
    const float* traj  = (const float*)d_in[0];
    const float* speed = (const float*)d_in[1];
    // d_in[2] = seq_start_end — groups contiguous & equal, unused
    const float* W1 = (const float*)d_in[3];
    const float* b1 = (const float*)d_in[4];
    const float* W2 = (const float*)d_in[5];
    const float* b2 = (const float*)d_in[6];
    const float* W3 = (const float*)d_in[7];
    const float* b3 = (const float*)d_in[8];

    float* out_mask = (float*)d_out;          // [G,N,N,T]
    float* out_vec  = out_mask + TOTAL_E;     // [G,N,N,T,2]

    const float cos_half_thr = cosf(0.5f * 0.8333f * 3.1415926f);

    // 1 wave = 256 elements; 4 waves/block => 1024 el/block; grid exact
    const int block = 256;
    const int grid  = TOTAL_E / 1024;         // 2560
    social_mfma_kernel<<<grid, block, 0, stream>>>(
        traj, speed, W1, b1, W2, b2, W3, b3, out_mask, out_vec, cos_half_thr);
}